// Round 6
// baseline (272.921 us; speedup 1.0000x reference)
//
#include <hip/hip_runtime.h>

#define NENT 8192
#define ROWS_PB 64                 // rows per pass1 block
#define NCHUNK (NENT / ROWS_PB)    // 128 partials per column
#define PART_BYTES ((size_t)NCHUNK * NENT * sizeof(unsigned long long))  // 8 MiB

typedef float floatx4 __attribute__((ext_vector_type(4)));

// pack: (float_bits(val) << 32) | ~row. Values nonneg -> uint order == value
// order; ties -> larger ~row == smaller row == first occurrence (jnp.argmax).
__device__ __forceinline__ unsigned long long pack_vi(float v, int i) {
    return ((unsigned long long)__float_as_uint(v) << 32) | (unsigned)(~i);
}

// Fused: block (x,y) scans rows [64y,64y+64) for cols [1024x,1024x+1024),
// writes packed partials, then the LAST-arriving block of col-chunk x
// reduces all 128 partials for its 1024 columns and writes d_out.
__global__ __launch_bounds__(256) void proj_fused_kernel(
    const float* __restrict__ emb, const float* __restrict__ R,
    const int* __restrict__ is_neg_p, unsigned long long* __restrict__ part,
    unsigned* __restrict__ counters, float* __restrict__ out) {
    const int t    = threadIdx.x;
    const int cx   = blockIdx.x;
    const int col0 = cx * 1024 + t * 4;
    const int row0 = blockIdx.y * ROWS_PB;
    const int neg  = *is_neg_p;  // uniform

    __shared__ float se[ROWS_PB];
    if (t < ROWS_PB) se[t] = emb[row0 + t];
    __syncthreads();

    float best0 = -1.f, best1 = -1.f, best2 = -1.f, best3 = -1.f;
    int   bi0 = 0, bi1 = 0, bi2 = 0, bi3 = 0;

    const float* rp = R + (size_t)row0 * NENT + col0;
#pragma unroll 16
    for (int ii = 0; ii < ROWS_PB; ++ii) {
        floatx4 r = __builtin_nontemporal_load(reinterpret_cast<const floatx4*>(rp));
        rp += NENT;
        if (neg) {  // NEG_SCALE == 1.0
            r.x = 1.f - fminf(1.f, r.x);
            r.y = 1.f - fminf(1.f, r.y);
            r.z = 1.f - fminf(1.f, r.z);
            r.w = 1.f - fminf(1.f, r.w);
        }
        const float e = se[ii];
        const int   i = row0 + ii;
        float p0 = e * r.x, p1 = e * r.y, p2 = e * r.z, p3 = e * r.w;
        if (p0 > best0) { best0 = p0; bi0 = i; }
        if (p1 > best1) { best1 = p1; bi1 = i; }
        if (p2 > best2) { best2 = p2; bi2 = i; }
        if (p3 > best3) { best3 = p3; bi3 = i; }
    }

    unsigned long long* wp = part + (size_t)blockIdx.y * NENT + col0;
    wp[0] = pack_vi(best0, bi0);
    wp[1] = pack_vi(best1, bi1);
    wp[2] = pack_vi(best2, bi2);
    wp[3] = pack_vi(best3, bi3);

    // arrival: release partials, count in
    __threadfence();
    __shared__ unsigned arrived;
    if (t == 0) arrived = atomicAdd(&counters[cx], 1u);
    __syncthreads();
    if (arrived != NCHUNK - 1) return;

    // last block for this col-chunk: acquire, reduce 128 partials x 1024 cols
    __threadfence();
    const unsigned long long* p = part + cx * 1024 + t;  // 4 cols/thread, coalesced
    unsigned long long b0 = 0ull, b1 = 0ull, b2 = 0ull, b3 = 0ull;
#pragma unroll 8
    for (int k = 0; k < NCHUNK; ++k) {
        const unsigned long long* pk = p + (size_t)k * NENT;
        unsigned long long v0 = pk[0], v1 = pk[256], v2 = pk[512], v3 = pk[768];
        b0 = v0 > b0 ? v0 : b0;
        b1 = v1 > b1 ? v1 : b1;
        b2 = v2 > b2 ? v2 : b2;
        b3 = v3 > b3 ? v3 : b3;
    }
    const int c0 = cx * 1024 + t;
    out[c0 +   0]       = __uint_as_float((unsigned)(b0 >> 32));
    out[c0 + 256]       = __uint_as_float((unsigned)(b1 >> 32));
    out[c0 + 512]       = __uint_as_float((unsigned)(b2 >> 32));
    out[c0 + 768]       = __uint_as_float((unsigned)(b3 >> 32));
    out[NENT + c0 +   0] = (float)(~(unsigned)(b0 & 0xFFFFFFFFull));
    out[NENT + c0 + 256] = (float)(~(unsigned)(b1 & 0xFFFFFFFFull));
    out[NENT + c0 + 512] = (float)(~(unsigned)(b2 & 0xFFFFFFFFull));
    out[NENT + c0 + 768] = (float)(~(unsigned)(b3 & 0xFFFFFFFFull));
}

// ---------- fallback path (atomics, 64 KiB ws) ----------
__global__ void init_ws_kernel(unsigned long long* __restrict__ ws) {
    int j = blockIdx.x * blockDim.x + threadIdx.x;
    if (j < NENT) ws[j] = 0ull;
}

__global__ __launch_bounds__(256) void proj_atomic_kernel(
    const float* __restrict__ emb, const float* __restrict__ R,
    const int* __restrict__ is_neg_p, unsigned long long* __restrict__ ws) {
    const int t    = threadIdx.x;
    const int col0 = blockIdx.x * 1024 + t * 4;
    const int row0 = blockIdx.y * 128;
    const int neg  = *is_neg_p;

    __shared__ float se[128];
    if (t < 128) se[t] = emb[row0 + t];
    __syncthreads();

    float best0 = -1.f, best1 = -1.f, best2 = -1.f, best3 = -1.f;
    int   bi0 = 0, bi1 = 0, bi2 = 0, bi3 = 0;

    const float* rp = R + (size_t)row0 * NENT + col0;
#pragma unroll 8
    for (int ii = 0; ii < 128; ++ii) {
        float4 r = *reinterpret_cast<const float4*>(rp);
        rp += NENT;
        if (neg) {
            r.x = 1.f - fminf(1.f, r.x);
            r.y = 1.f - fminf(1.f, r.y);
            r.z = 1.f - fminf(1.f, r.z);
            r.w = 1.f - fminf(1.f, r.w);
        }
        const float e = se[ii];
        const int   i = row0 + ii;
        float p0 = e * r.x, p1 = e * r.y, p2 = e * r.z, p3 = e * r.w;
        if (p0 > best0) { best0 = p0; bi0 = i; }
        if (p1 > best1) { best1 = p1; bi1 = i; }
        if (p2 > best2) { best2 = p2; bi2 = i; }
        if (p3 > best3) { best3 = p3; bi3 = i; }
    }
    atomicMax(ws + col0 + 0, pack_vi(best0, bi0));
    atomicMax(ws + col0 + 1, pack_vi(best1, bi1));
    atomicMax(ws + col0 + 2, pack_vi(best2, bi2));
    atomicMax(ws + col0 + 3, pack_vi(best3, bi3));
}

__global__ void unpack_kernel(const unsigned long long* __restrict__ ws,
                              float* __restrict__ out) {
    int j = blockIdx.x * blockDim.x + threadIdx.x;
    if (j >= NENT) return;
    unsigned long long p = ws[j];
    out[j]        = __uint_as_float((unsigned)(p >> 32));
    out[NENT + j] = (float)(~(unsigned)(p & 0xFFFFFFFFull));
}

extern "C" void kernel_launch(void* const* d_in, const int* in_sizes, int n_in,
                              void* d_out, int out_size, void* d_ws, size_t ws_size,
                              hipStream_t stream) {
    const float* emb      = (const float*)d_in[0];
    const float* R        = (const float*)d_in[1];
    const int*   is_neg_p = (const int*)d_in[2];
    float* out            = (float*)d_out;
    unsigned long long* part = (unsigned long long*)d_ws;
    unsigned* counters       = (unsigned*)((char*)d_ws + PART_BYTES);

    if (ws_size >= PART_BYTES + 64) {
        (void)hipMemsetAsync(counters, 0, 8 * sizeof(unsigned), stream);
        dim3 g1(8, NCHUNK);
        proj_fused_kernel<<<g1, 256, 0, stream>>>(emb, R, is_neg_p, part,
                                                  counters, out);
    } else {
        init_ws_kernel<<<NENT / 256, 256, 0, stream>>>(part);
        dim3 g1(8, 64);
        proj_atomic_kernel<<<g1, 256, 0, stream>>>(emb, R, is_neg_p, part);
        unpack_kernel<<<NENT / 256, 256, 0, stream>>>(part, out);
    }
}

// Round 7
// 45.300 us; speedup vs baseline: 6.0248x; 6.0248x over previous
//
#include <hip/hip_runtime.h>

#define NENT 8192
#define COLS_PB 32        // columns owned per block (one 128B line span)
#define NPHASE 16         // row phases per block (512 threads = 32 x 16)
#define ROWS_PP (NENT / NPHASE)   // 512 rows per phase

// pack: (float_bits(val) << 32) | ~row. Values nonneg -> uint order == value
// order; ties -> larger ~row == smaller row == first occurrence (jnp.argmax).
__device__ __forceinline__ unsigned long long pack_vi(float v, int i) {
    return ((unsigned long long)__float_as_uint(v) << 32) | (unsigned)(~i);
}

// One block owns cols [32*cx, 32*cx+32) across ALL rows: no partials, no
// second kernel, no fences. t = p*32 + c: lane group 0-31 / 32-63 each read
// one full 128B line per load instruction.
__global__ __launch_bounds__(512, 1) void proj_colown_kernel(
    const float* __restrict__ emb, const float* __restrict__ R,
    const int* __restrict__ is_neg_p, float* __restrict__ out) {
    const int t   = threadIdx.x;
    const int c   = t & (COLS_PB - 1);
    const int p   = t >> 5;                 // phase 0..15
    const int cx  = blockIdx.x;
    const int col = cx * COLS_PB + c;
    const int neg = *is_neg_p;              // uniform

    __shared__ float se[NENT];              // full embedding row, 32 KB
    __shared__ unsigned long long red[NPHASE][COLS_PB];  // 4 KB

#pragma unroll
    for (int j = 0; j < NENT / 512; ++j) se[t + j * 512] = emb[t + j * 512];
    __syncthreads();

    const float* rp = R + (size_t)(p * ROWS_PP) * NENT + col;
    const float* ep = se + p * ROWS_PP;

    float best = -1.f;
    int   bk   = 0;   // row index within this phase

#pragma unroll 16
    for (int k = 0; k < ROWS_PP; ++k) {
        float v = rp[(size_t)k * NENT];
        if (neg) v = 1.f - fminf(1.f, v);   // NEG_SCALE == 1.0
        float pr = ep[k] * v;
        if (pr > best) { best = pr; bk = k; }
    }

    red[p][c] = pack_vi(best, p * ROWS_PP + bk);
    __syncthreads();

    if (t < COLS_PB) {
        unsigned long long b = red[0][t];
#pragma unroll
        for (int q = 1; q < NPHASE; ++q) {
            unsigned long long v = red[q][t];
            b = v > b ? v : b;
        }
        const int oc = cx * COLS_PB + t;
        out[oc]        = __uint_as_float((unsigned)(b >> 32));
        out[NENT + oc] = (float)(~(unsigned)(b & 0xFFFFFFFFull));
    }
}

extern "C" void kernel_launch(void* const* d_in, const int* in_sizes, int n_in,
                              void* d_out, int out_size, void* d_ws, size_t ws_size,
                              hipStream_t stream) {
    const float* emb      = (const float*)d_in[0];
    const float* R        = (const float*)d_in[1];
    const int*   is_neg_p = (const int*)d_in[2];
    float* out            = (float*)d_out;

    proj_colown_kernel<<<NENT / COLS_PB, 512, 0, stream>>>(emb, R, is_neg_p, out);
}